// Round 15
// baseline (230.892 us; speedup 1.0000x reference)
//
#include <hip/hip_runtime.h>

// Problem constants
#define NHEADS   8
#define EMB_     128
#define BT_      512        // b*t = 4*128
#define HIN_     1024
#define NQ_      4096       // BT_*NHEADS
#define NKEY_    50000
#define NPAD_    50048      // 3128 groups of 16 keys
#define NGRP_    3128       // key groups of 16
#define GPS_     68         // groups per slice: 46*68 = 3128, 68 = 4*17
#define NSLICES_ 46         // grid 16x46 = 736 blocks (r13 best geometry)

// scale = 128^-0.25 (reference) * log2(e) (scores land directly in exp2 domain)
#define QSCALE   (0.29730177875068026f * 1.4426950408889634f)

typedef __attribute__((ext_vector_type(8))) short short8v;   // 8 bf16 = 4 VGPRs
typedef __attribute__((ext_vector_type(4))) float float4v;   // MFMA C/D frag

#if __has_builtin(__builtin_amdgcn_exp2f)
#define EXP2F(x) __builtin_amdgcn_exp2f(x)
#else
#define EXP2F(x) exp2f(x)
#endif

__device__ __forceinline__ short f2bf(float f) {  // fp32 -> bf16 bits, RNE
  unsigned u = __float_as_uint(f);
  u += 0x7fffu + ((u >> 16) & 1u);
  return (short)(u >> 16);
}

#if __has_builtin(__builtin_amdgcn_cvt_pk_bf16_f32)
typedef __attribute__((ext_vector_type(2))) __bf16 bf16x2;
__device__ __forceinline__ unsigned pk2(float a, float b) {
  bf16x2 r = __builtin_amdgcn_cvt_pk_bf16_f32(a, b);
  union { bf16x2 v; unsigned u; } c; c.v = r; return c.u;
}
#else
__device__ __forceinline__ unsigned pk2(float a, float b) {
  return (unsigned)(unsigned short)f2bf(a) | ((unsigned)(unsigned short)f2bf(b) << 16);
}
#endif

// ---------------------------------------------------------------------------
// Kernel 0: keys fp32 -> bf16 in MFMA B-FRAGMENT ORDER (r13). Dense float4
// loads; 8 B scattered stores (posted). Group g, k-slice ks, lane l holds
// key (g*16 + (l&15)), elements ks*32 + (l>>4)*8 .. +7 at
// keys_fr[((g*4+ks)*64 + l)*8].
// ---------------------------------------------------------------------------
__global__ __launch_bounds__(256) void convert_kernel(
    const float* __restrict__ keys, const float* __restrict__ values,
    short* __restrict__ keys_fr, float* __restrict__ vpad) {
#pragma unroll
  for (int j = 0; j < 2; ++j) {
    int g = blockIdx.x * 512 + j * 256 + threadIdx.x;  // float4 id, dense
    int key  = g >> 5;                           // 32 float4 per key row
    int posf = g & 31;
    int lc   = posf >> 1;                        // logical 8-elem chunk 0..15
    int half = posf & 1;
    union { short4 s; unsigned u[2]; } o;
    if (key < NKEY_) {
      float4 v = ((const float4*)keys)[g];       // lane stride 16 B: dense
      o.u[0] = pk2(v.x, v.y);
      o.u[1] = pk2(v.z, v.w);
    } else {
      o.u[0] = 0; o.u[1] = 0;                    // pad rows -> score 0
    }
    int grp = key >> 4, kln = key & 15;
    int ks = lc >> 2, q = lc & 3;                // element range ks*32+q*8
    *(short4*)(keys_fr + ((grp * 4 + ks) * 64 + q * 16 + kln) * 8 + half * 4) = o.s;
    if (posf == 0) vpad[key] = (key < NKEY_) ? values[key] : 0.f;
  }
}

// ---------------------------------------------------------------------------
// Kernel 1: q = (x @ Wq^T) * QSCALE -> bf16 (r9: rolled loop, named-scalar
// double buffer, default register budget).
// ---------------------------------------------------------------------------
__global__ __launch_bounds__(256) void proj_kernel(
    const float* __restrict__ x, const float* __restrict__ Wq,
    short* __restrict__ qb) {
  const int wave = threadIdx.x >> 6, lane = threadIdx.x & 63;
  const int quad = lane >> 4, ln = lane & 15;
  const int tile = blockIdx.x * 4 + wave;        // 2048 tiles
  const int mt = tile >> 6, ot = tile & 63;      // 32 m-tiles x 64 o-tiles
  const float* xrow = x  + (mt * 16 + ln) * HIN_ + quad * 8;
  const float* wrow = Wq + (ot * 16 + ln) * HIN_ + quad * 8;
  float4v d = {0.f, 0.f, 0.f, 0.f};

  float4 xa0 = *(const float4*)(xrow);
  float4 xa1 = *(const float4*)(xrow + 4);
  float4 wa0 = *(const float4*)(wrow);
  float4 wa1 = *(const float4*)(wrow + 4);
  float4 xb0 = *(const float4*)(xrow + 32);
  float4 xb1 = *(const float4*)(xrow + 36);
  float4 wb0 = *(const float4*)(wrow + 32);
  float4 wb1 = *(const float4*)(wrow + 36);

#pragma unroll 1
  for (int k0 = 0; k0 < HIN_; k0 += 64) {
    union { short8v s8; unsigned u[4]; } af, bf;
    af.u[0] = pk2(xa0.x, xa0.y); af.u[1] = pk2(xa0.z, xa0.w);
    af.u[2] = pk2(xa1.x, xa1.y); af.u[3] = pk2(xa1.z, xa1.w);
    bf.u[0] = pk2(wa0.x, wa0.y); bf.u[1] = pk2(wa0.z, wa0.w);
    bf.u[2] = pk2(wa1.x, wa1.y); bf.u[3] = pk2(wa1.z, wa1.w);
    if (k0 + 64 < HIN_) {
      xa0 = *(const float4*)(xrow + k0 + 64);
      xa1 = *(const float4*)(xrow + k0 + 68);
      wa0 = *(const float4*)(wrow + k0 + 64);
      wa1 = *(const float4*)(wrow + k0 + 68);
    }
    d = __builtin_amdgcn_mfma_f32_16x16x32_bf16(af.s8, bf.s8, d, 0, 0, 0);

    af.u[0] = pk2(xb0.x, xb0.y); af.u[1] = pk2(xb0.z, xb0.w);
    af.u[2] = pk2(xb1.x, xb1.y); af.u[3] = pk2(xb1.z, xb1.w);
    bf.u[0] = pk2(wb0.x, wb0.y); bf.u[1] = pk2(wb0.z, wb0.w);
    bf.u[2] = pk2(wb1.x, wb1.y); bf.u[3] = pk2(wb1.z, wb1.w);
    if (k0 + 96 < HIN_) {
      xb0 = *(const float4*)(xrow + k0 + 96);
      xb1 = *(const float4*)(xrow + k0 + 100);
      wb0 = *(const float4*)(wrow + k0 + 96);
      wb1 = *(const float4*)(wrow + k0 + 100);
    }
    d = __builtin_amdgcn_mfma_f32_16x16x32_bf16(af.s8, bf.s8, d, 0, 0, 0);
  }
#pragma unroll
  for (int r2 = 0; r2 < 4; ++r2)
    qb[(mt * 16 + quad * 4 + r2) * HIN_ + ot * 16 + ln] = f2bf(d[r2] * QSCALE);
}

// ---------------------------------------------------------------------------
// Kernel 2: flash-decoding attention, no LDS / no barriers, DEPTH-4 register
// pipeline. r13 (depth 2) issued group g+2's loads only ~250 cy before use
// -- at the edge of L2 latency, so every group exposed a residual stall
// (71 us vs ~27 us overlapped ideal). Depth 4 puts ~500+ cy between issue
// and consume. +32 VGPR (~145 total): residency cap 3 waves/SIMD, still >=
// the grid-imposed 2.875 -> no occupancy loss. Buffer index is a fully
// unrolled constant (not the r9 dynamic-index spill trap). Grid reverted to
// 16x46 (r14's 16x63 regressed: TLP is not the bound).
// ---------------------------------------------------------------------------
__global__ __launch_bounds__(256) void attn_kernel(
    const short* __restrict__ qb,        // bf16 [NQ_][128]
    const short* __restrict__ keys_fr,   // bf16, B-fragment order
    const float* __restrict__ vpad,      // [NPAD_]
    float* __restrict__ partials) {      // [NQ_][NSLICES_][2] = {l, acc}
  const int t     = threadIdx.x;
  const int wave  = t >> 6;
  const int lane  = t & 63;
  const int quad  = lane >> 4;
  const int ln    = lane & 15;
  const int qbase = blockIdx.x * 256 + wave * 64;
  const int slice = blockIdx.y;
  const int g0    = slice * GPS_;
  const int g1    = g0 + GPS_;                   // all slices full, GPS_ = 4*17

  short8v a[4][4];
#pragma unroll
  for (int sub = 0; sub < 4; ++sub)
#pragma unroll
    for (int ks = 0; ks < 4; ++ks)
      a[sub][ks] = *(const short8v*)(qb + (qbase + sub * 16 + ln) * EMB_ + ks * 32 + quad * 8);

  float lsum[4][4], asum[4][4];
#pragma unroll
  for (int i = 0; i < 4; ++i)
#pragma unroll
    for (int j = 0; j < 4; ++j) { lsum[i][j] = 0.f; asum[i][j] = 0.f; }

  short8v b[4][4];                               // depth-4 ring of B-frags
  float vv[4];
#pragma unroll
  for (int i = 0; i < 4; ++i) {                  // preload groups g0..g0+3
#pragma unroll
    for (int ks = 0; ks < 4; ++ks)
      b[i][ks] = *(const short8v*)(keys_fr + (((g0 + i) * 4 + ks) * 64 + lane) * 8);
    vv[i] = vpad[(g0 + i) * 16 + ln];
  }

#pragma unroll 1
  for (int g = g0; g < g1; g += 4) {
#pragma unroll
    for (int i = 0; i < 4; ++i) {                // i is a compile-time constant
      float4v d[4];
#pragma unroll
      for (int sub = 0; sub < 4; ++sub) d[sub] = (float4v){0.f, 0.f, 0.f, 0.f};
#pragma unroll
      for (int ks = 0; ks < 4; ++ks)             // ks outer: 4 indep chains
#pragma unroll
        for (int sub = 0; sub < 4; ++sub)
          d[sub] = __builtin_amdgcn_mfma_f32_16x16x32_bf16(a[sub][ks], b[i][ks], d[sub], 0, 0, 0);
      float v = vv[i];
      if (g + 4 + i < g1) {                      // refill slot i with g+4+i
#pragma unroll
        for (int ks = 0; ks < 4; ++ks)
          b[i][ks] = *(const short8v*)(keys_fr + (((g + 4 + i) * 4 + ks) * 64 + lane) * 8);
        vv[i] = vpad[(g + 4 + i) * 16 + ln];
      }
#pragma unroll
      for (int sub = 0; sub < 4; ++sub)
#pragma unroll
        for (int r2 = 0; r2 < 4; ++r2) {
          float p = EXP2F(d[sub][r2]);
          lsum[sub][r2] += p;
          asum[sub][r2] = fmaf(p, v, asum[sub][r2]);
        }
    }
  }

  // reduce over the 16 key-column lanes (same quad); lane ln==0 writes
#pragma unroll
  for (int sub = 0; sub < 4; ++sub)
#pragma unroll
    for (int r2 = 0; r2 < 4; ++r2) {
      float L = lsum[sub][r2], A = asum[sub][r2];
#pragma unroll
      for (int m = 1; m < 16; m <<= 1) {
        L += __shfl_xor(L, m, 64);
        A += __shfl_xor(A, m, 64);
      }
      if (ln == 0) {
        int q = qbase + sub * 16 + quad * 4 + r2;
        partials[(q * NSLICES_ + slice) * 2 + 0] = L;
        partials[(q * NSLICES_ + slice) * 2 + 1] = A;
      }
    }
}

// ---------------------------------------------------------------------------
// Kernel 3: combine slice partials, mean over heads, add curiosity.
// 46 slices * 2 floats = 23 float4 per (bt,head).
// ---------------------------------------------------------------------------
__global__ __launch_bounds__(256) void finalize_kernel(
    const float* __restrict__ partials, const float* __restrict__ cur,
    float* __restrict__ out) {
  int tid = blockIdx.x * 256 + threadIdx.x;      // 4096 threads
  int bt = tid >> 3, h = tid & 7;
  int q = bt * NHEADS + h;
  const float4* p = (const float4*)(partials + q * NSLICES_ * 2);
  float sl = 0.f, sa = 0.f;
#pragma unroll
  for (int i = 0; i < NSLICES_ / 2; ++i) {       // 2 slices per float4
    float4 v = p[i];
    sl += v.x + v.z;
    sa += v.y + v.w;
  }
  float r = sa / sl;
  r += __shfl_xor(r, 1, 64);
  r += __shfl_xor(r, 2, 64);
  r += __shfl_xor(r, 4, 64);
  if (h == 0) out[bt] = r * (1.f / NHEADS) + cur[bt];
}

// ---------------------------------------------------------------------------
extern "C" void kernel_launch(void* const* d_in, const int* in_sizes, int n_in,
                              void* d_out, int out_size, void* d_ws, size_t ws_size,
                              hipStream_t stream) {
  (void)in_sizes; (void)n_in; (void)out_size; (void)ws_size;
  const float* x      = (const float*)d_in[0];   // (4,128,1024)
  const float* cur    = (const float*)d_in[1];   // (4,128)
  const float* Wq     = (const float*)d_in[2];   // (1024,1024)
  const float* keys   = (const float*)d_in[3];   // (50000,128)
  const float* values = (const float*)d_in[4];   // (50000,)
  float* out = (float*)d_out;                    // (4,128,1) fp32

  // workspace layout (16B-aligned), ~15.6 MB total
  char* ws = (char*)d_ws;
  short* keys_fr = (short*)(ws);                        // 12,812,288 B
  float* vpad    = (float*)(ws + 12812288);             //    200,192 B
  short* qb      = (short*)(ws + 13012480);             //  1,048,576 B
  float* part    = (float*)(ws + 14061056);             //  1,507,328 B (46 slices)

  hipLaunchKernelGGL(convert_kernel, dim3((NPAD_ * 32) / 512), dim3(256), 0, stream,
                     keys, values, keys_fr, vpad);
  hipLaunchKernelGGL(proj_kernel, dim3(512), dim3(256), 0, stream, x, Wq, qb);
  hipLaunchKernelGGL(attn_kernel, dim3(16, NSLICES_), dim3(256), 0, stream,
                     qb, keys_fr, vpad, part);
  hipLaunchKernelGGL(finalize_kernel, dim3(16), dim3(256), 0, stream, part, cur, out);
}

// Round 16
// 175.116 us; speedup vs baseline: 1.3185x; 1.3185x over previous
//
#include <hip/hip_runtime.h>

// Problem constants
#define NHEADS   8
#define EMB_     128
#define BT_      512        // b*t = 4*128
#define HIN_     1024
#define NQ_      4096       // BT_*NHEADS
#define NKEY_    50000
#define NPAD_    50048      // 3128 groups of 16 keys
#define NGRP_    3128       // key groups of 16
#define GPS_     68         // groups per slice: 46*68 = 3128 exactly
#define NSLICES_ 46         // grid 16x46 = 736 blocks (best measured: r13)

// scale = 128^-0.25 (reference) * log2(e) (scores land directly in exp2 domain)
#define QSCALE   (0.29730177875068026f * 1.4426950408889634f)

typedef __attribute__((ext_vector_type(8))) short short8v;   // 8 bf16 = 4 VGPRs
typedef __attribute__((ext_vector_type(4))) float float4v;   // MFMA C/D frag

#if __has_builtin(__builtin_amdgcn_exp2f)
#define EXP2F(x) __builtin_amdgcn_exp2f(x)
#else
#define EXP2F(x) exp2f(x)
#endif

__device__ __forceinline__ short f2bf(float f) {  // fp32 -> bf16 bits, RNE
  unsigned u = __float_as_uint(f);
  u += 0x7fffu + ((u >> 16) & 1u);
  return (short)(u >> 16);
}

#if __has_builtin(__builtin_amdgcn_cvt_pk_bf16_f32)
typedef __attribute__((ext_vector_type(2))) __bf16 bf16x2;
__device__ __forceinline__ unsigned pk2(float a, float b) {
  bf16x2 r = __builtin_amdgcn_cvt_pk_bf16_f32(a, b);
  union { bf16x2 v; unsigned u; } c; c.v = r; return c.u;
}
#else
__device__ __forceinline__ unsigned pk2(float a, float b) {
  return (unsigned)(unsigned short)f2bf(a) | ((unsigned)(unsigned short)f2bf(b) << 16);
}
#endif

// ---------------------------------------------------------------------------
// Kernel 0: keys fp32 -> bf16 in MFMA B-FRAGMENT ORDER. Dense float4 loads;
// 8 B scattered stores (posted). Group g, k-slice ks, lane l holds key
// (g*16 + (l&15)), elements ks*32 + (l>>4)*8 .. +7 at
// keys_fr[((g*4+ks)*64 + l)*8].
// ---------------------------------------------------------------------------
__global__ __launch_bounds__(256) void convert_kernel(
    const float* __restrict__ keys, const float* __restrict__ values,
    short* __restrict__ keys_fr, float* __restrict__ vpad) {
#pragma unroll
  for (int j = 0; j < 2; ++j) {
    int g = blockIdx.x * 512 + j * 256 + threadIdx.x;  // float4 id, dense
    int key  = g >> 5;                           // 32 float4 per key row
    int posf = g & 31;
    int lc   = posf >> 1;                        // logical 8-elem chunk 0..15
    int half = posf & 1;
    union { short4 s; unsigned u[2]; } o;
    if (key < NKEY_) {
      float4 v = ((const float4*)keys)[g];       // lane stride 16 B: dense
      o.u[0] = pk2(v.x, v.y);
      o.u[1] = pk2(v.z, v.w);
    } else {
      o.u[0] = 0; o.u[1] = 0;                    // pad rows -> score 0
    }
    int grp = key >> 4, kln = key & 15;
    int ks = lc >> 2, q = lc & 3;                // element range ks*32+q*8
    *(short4*)(keys_fr + ((grp * 4 + ks) * 64 + q * 16 + kln) * 8 + half * 4) = o.s;
    if (posf == 0) vpad[key] = (key < NKEY_) ? values[key] : 0.f;
  }
}

// ---------------------------------------------------------------------------
// Kernel 1: q = (x @ Wq^T) * QSCALE -> bf16 (r9: rolled loop, named-scalar
// double buffer, default register budget).
// ---------------------------------------------------------------------------
__global__ __launch_bounds__(256) void proj_kernel(
    const float* __restrict__ x, const float* __restrict__ Wq,
    short* __restrict__ qb) {
  const int wave = threadIdx.x >> 6, lane = threadIdx.x & 63;
  const int quad = lane >> 4, ln = lane & 15;
  const int tile = blockIdx.x * 4 + wave;        // 2048 tiles
  const int mt = tile >> 6, ot = tile & 63;      // 32 m-tiles x 64 o-tiles
  const float* xrow = x  + (mt * 16 + ln) * HIN_ + quad * 8;
  const float* wrow = Wq + (ot * 16 + ln) * HIN_ + quad * 8;
  float4v d = {0.f, 0.f, 0.f, 0.f};

  float4 xa0 = *(const float4*)(xrow);
  float4 xa1 = *(const float4*)(xrow + 4);
  float4 wa0 = *(const float4*)(wrow);
  float4 wa1 = *(const float4*)(wrow + 4);
  float4 xb0 = *(const float4*)(xrow + 32);
  float4 xb1 = *(const float4*)(xrow + 36);
  float4 wb0 = *(const float4*)(wrow + 32);
  float4 wb1 = *(const float4*)(wrow + 36);

#pragma unroll 1
  for (int k0 = 0; k0 < HIN_; k0 += 64) {
    union { short8v s8; unsigned u[4]; } af, bf;
    af.u[0] = pk2(xa0.x, xa0.y); af.u[1] = pk2(xa0.z, xa0.w);
    af.u[2] = pk2(xa1.x, xa1.y); af.u[3] = pk2(xa1.z, xa1.w);
    bf.u[0] = pk2(wa0.x, wa0.y); bf.u[1] = pk2(wa0.z, wa0.w);
    bf.u[2] = pk2(wa1.x, wa1.y); bf.u[3] = pk2(wa1.z, wa1.w);
    if (k0 + 64 < HIN_) {
      xa0 = *(const float4*)(xrow + k0 + 64);
      xa1 = *(const float4*)(xrow + k0 + 68);
      wa0 = *(const float4*)(wrow + k0 + 64);
      wa1 = *(const float4*)(wrow + k0 + 68);
    }
    d = __builtin_amdgcn_mfma_f32_16x16x32_bf16(af.s8, bf.s8, d, 0, 0, 0);

    af.u[0] = pk2(xb0.x, xb0.y); af.u[1] = pk2(xb0.z, xb0.w);
    af.u[2] = pk2(xb1.x, xb1.y); af.u[3] = pk2(xb1.z, xb1.w);
    bf.u[0] = pk2(wb0.x, wb0.y); bf.u[1] = pk2(wb0.z, wb0.w);
    bf.u[2] = pk2(wb1.x, wb1.y); bf.u[3] = pk2(wb1.z, wb1.w);
    if (k0 + 96 < HIN_) {
      xb0 = *(const float4*)(xrow + k0 + 96);
      xb1 = *(const float4*)(xrow + k0 + 100);
      wb0 = *(const float4*)(wrow + k0 + 96);
      wb1 = *(const float4*)(wrow + k0 + 100);
    }
    d = __builtin_amdgcn_mfma_f32_16x16x32_bf16(af.s8, bf.s8, d, 0, 0, 0);
  }
#pragma unroll
  for (int r2 = 0; r2 < 4; ++r2)
    qb[(mt * 16 + quad * 4 + r2) * HIN_ + ot * 16 + ln] = f2bf(d[r2] * QSCALE);
}

// ---------------------------------------------------------------------------
// Kernel 2: flash-decoding attention, no LDS / no barriers, depth-2 register
// ping-pong (r13 EXACT -- best measured: 71.3 us). Depth-2 at 108 VGPR sits
// just under the 128-VGPR occupancy cliff; depth-4 (r15: 160 VGPR, occ
// 10.6%, 122 us) and extra TLP (r14) both regress. ks-outer MFMA = 4
// independent accumulator chains (r12, +5%).
// ---------------------------------------------------------------------------
__global__ __launch_bounds__(256) void attn_kernel(
    const short* __restrict__ qb,        // bf16 [NQ_][128]
    const short* __restrict__ keys_fr,   // bf16, B-fragment order
    const float* __restrict__ vpad,      // [NPAD_]
    float* __restrict__ partials) {      // [NQ_][NSLICES_][2] = {l, acc}
  const int t     = threadIdx.x;
  const int wave  = t >> 6;
  const int lane  = t & 63;
  const int quad  = lane >> 4;
  const int ln    = lane & 15;
  const int qbase = blockIdx.x * 256 + wave * 64;
  const int slice = blockIdx.y;
  const int g0    = slice * GPS_;
  const int g1    = g0 + GPS_;                   // all slices full (46*68)

  short8v a[4][4];
#pragma unroll
  for (int sub = 0; sub < 4; ++sub)
#pragma unroll
    for (int ks = 0; ks < 4; ++ks)
      a[sub][ks] = *(const short8v*)(qb + (qbase + sub * 16 + ln) * EMB_ + ks * 32 + quad * 8);

  float lsum[4][4], asum[4][4];
#pragma unroll
  for (int i = 0; i < 4; ++i)
#pragma unroll
    for (int j = 0; j < 4; ++j) { lsum[i][j] = 0.f; asum[i][j] = 0.f; }

  short8v bA[4], bB[4];                          // register ping-pong
  float vA, vB;
#pragma unroll
  for (int ks = 0; ks < 4; ++ks)                 // preload group g0 / g0+1
    bA[ks] = *(const short8v*)(keys_fr + ((g0 * 4 + ks) * 64 + lane) * 8);
  vA = vpad[g0 * 16 + ln];
#pragma unroll
  for (int ks = 0; ks < 4; ++ks)
    bB[ks] = *(const short8v*)(keys_fr + (((g0 + 1) * 4 + ks) * 64 + lane) * 8);
  vB = vpad[(g0 + 1) * 16 + ln];

#pragma unroll 1
  for (int g = g0; g < g1; g += 2) {
    // ---- even group: consume bA/vA, refill bA with g+2 ----
    {
      float4v d[4];
#pragma unroll
      for (int sub = 0; sub < 4; ++sub) d[sub] = (float4v){0.f, 0.f, 0.f, 0.f};
#pragma unroll
      for (int ks = 0; ks < 4; ++ks)             // ks outer: 4 indep chains
#pragma unroll
        for (int sub = 0; sub < 4; ++sub)
          d[sub] = __builtin_amdgcn_mfma_f32_16x16x32_bf16(a[sub][ks], bA[ks], d[sub], 0, 0, 0);
      if (g + 2 < g1) {                          // issue while MFMAs run
#pragma unroll
        for (int ks = 0; ks < 4; ++ks)
          bA[ks] = *(const short8v*)(keys_fr + (((g + 2) * 4 + ks) * 64 + lane) * 8);
      }
      float vv = vA;
      if (g + 2 < g1) vA = vpad[(g + 2) * 16 + ln];
#pragma unroll
      for (int sub = 0; sub < 4; ++sub)
#pragma unroll
        for (int r2 = 0; r2 < 4; ++r2) {
          float p = EXP2F(d[sub][r2]);
          lsum[sub][r2] += p;
          asum[sub][r2] = fmaf(p, vv, asum[sub][r2]);
        }
    }
    // ---- odd group: consume bB/vB, refill bB with g+3 ----
    {
      float4v d[4];
#pragma unroll
      for (int sub = 0; sub < 4; ++sub) d[sub] = (float4v){0.f, 0.f, 0.f, 0.f};
#pragma unroll
      for (int ks = 0; ks < 4; ++ks)
#pragma unroll
        for (int sub = 0; sub < 4; ++sub)
          d[sub] = __builtin_amdgcn_mfma_f32_16x16x32_bf16(a[sub][ks], bB[ks], d[sub], 0, 0, 0);
      if (g + 3 < g1) {
#pragma unroll
        for (int ks = 0; ks < 4; ++ks)
          bB[ks] = *(const short8v*)(keys_fr + (((g + 3) * 4 + ks) * 64 + lane) * 8);
      }
      float vv = vB;
      if (g + 3 < g1) vB = vpad[(g + 3) * 16 + ln];
#pragma unroll
      for (int sub = 0; sub < 4; ++sub)
#pragma unroll
        for (int r2 = 0; r2 < 4; ++r2) {
          float p = EXP2F(d[sub][r2]);
          lsum[sub][r2] += p;
          asum[sub][r2] = fmaf(p, vv, asum[sub][r2]);
        }
    }
  }

  // reduce over the 16 key-column lanes (same quad); lane ln==0 writes
#pragma unroll
  for (int sub = 0; sub < 4; ++sub)
#pragma unroll
    for (int r2 = 0; r2 < 4; ++r2) {
      float L = lsum[sub][r2], A = asum[sub][r2];
#pragma unroll
      for (int m = 1; m < 16; m <<= 1) {
        L += __shfl_xor(L, m, 64);
        A += __shfl_xor(A, m, 64);
      }
      if (ln == 0) {
        int q = qbase + sub * 16 + quad * 4 + r2;
        partials[(q * NSLICES_ + slice) * 2 + 0] = L;
        partials[(q * NSLICES_ + slice) * 2 + 1] = A;
      }
    }
}

// ---------------------------------------------------------------------------
// Kernel 3: combine slice partials, mean over heads, add curiosity.
// ---------------------------------------------------------------------------
__global__ __launch_bounds__(256) void finalize_kernel(
    const float* __restrict__ partials, const float* __restrict__ cur,
    float* __restrict__ out) {
  int tid = blockIdx.x * 256 + threadIdx.x;      // 4096 threads
  int bt = tid >> 3, h = tid & 7;
  int q = bt * NHEADS + h;
  const float4* p = (const float4*)(partials + q * NSLICES_ * 2);
  float sl = 0.f, sa = 0.f;
#pragma unroll
  for (int i = 0; i < NSLICES_ / 2; ++i) {       // 2 slices per float4
    float4 v = p[i];
    sl += v.x + v.z;
    sa += v.y + v.w;
  }
  float r = sa / sl;
  r += __shfl_xor(r, 1, 64);
  r += __shfl_xor(r, 2, 64);
  r += __shfl_xor(r, 4, 64);
  if (h == 0) out[bt] = r * (1.f / NHEADS) + cur[bt];
}

// ---------------------------------------------------------------------------
extern "C" void kernel_launch(void* const* d_in, const int* in_sizes, int n_in,
                              void* d_out, int out_size, void* d_ws, size_t ws_size,
                              hipStream_t stream) {
  (void)in_sizes; (void)n_in; (void)out_size; (void)ws_size;
  const float* x      = (const float*)d_in[0];   // (4,128,1024)
  const float* cur    = (const float*)d_in[1];   // (4,128)
  const float* Wq     = (const float*)d_in[2];   // (1024,1024)
  const float* keys   = (const float*)d_in[3];   // (50000,128)
  const float* values = (const float*)d_in[4];   // (50000,)
  float* out = (float*)d_out;                    // (4,128,1) fp32

  // workspace layout (16B-aligned), ~15.6 MB total
  char* ws = (char*)d_ws;
  short* keys_fr = (short*)(ws);                        // 12,812,288 B
  float* vpad    = (float*)(ws + 12812288);             //    200,192 B
  short* qb      = (short*)(ws + 13012480);             //  1,048,576 B
  float* part    = (float*)(ws + 14061056);             //  1,507,328 B (46 slices)

  hipLaunchKernelGGL(convert_kernel, dim3((NPAD_ * 32) / 512), dim3(256), 0, stream,
                     keys, values, keys_fr, vpad);
  hipLaunchKernelGGL(proj_kernel, dim3(512), dim3(256), 0, stream, x, Wq, qb);
  hipLaunchKernelGGL(attn_kernel, dim3(16, NSLICES_), dim3(256), 0, stream,
                     qb, keys_fr, vpad, part);
  hipLaunchKernelGGL(finalize_kernel, dim3(16), dim3(256), 0, stream, part, cur, out);
}